// Round 5
// baseline (82.411 us; speedup 1.0000x reference)
//
#include <hip/hip_runtime.h>
#include <math.h>

typedef __attribute__((ext_vector_type(8))) short bf16x8;
typedef __attribute__((ext_vector_type(4))) float f32x4;

static __device__ __forceinline__ unsigned short f2bf(float f) {
  union { float f; unsigned u; } a; a.f = f;
  unsigned u = a.u;
  unsigned r = u + 0x7FFF + ((u >> 16) & 1);   // RNE
  return (unsigned short)(r >> 16);
}
static __device__ __forceinline__ float bf2f(unsigned short h) {
  union { unsigned u; float f; } a; a.u = ((unsigned)h) << 16;
  return a.f;
}
static __device__ __forceinline__ float tanh_fast(float x) {
  float ax = fabsf(x);
  float e = __expf(-2.0f * ax);
  float t = (1.0f - e) / (1.0f + e);
  t = (ax > 10.0f) ? 1.0f : t;
  return (x < 0.0f) ? -t : t;
}

// All three weight transpose+splits in one launch.
__global__ __launch_bounds__(256) void k_split_all(
    const float* __restrict__ W1, const float* __restrict__ W2, const float* __restrict__ Wv,
    unsigned short* __restrict__ W1Th, unsigned short* __restrict__ W1Tl,
    unsigned short* __restrict__ W2Th, unsigned short* __restrict__ W2Tl,
    unsigned short* __restrict__ WvTh, unsigned short* __restrict__ WvTl)
{
  const int b = blockIdx.x;
  const float* W; unsigned short *Th, *Tl; int Kd, Nd, base;
  if (b < 1024)      { W = W1; Th = W1Th; Tl = W1Tl; Kd = 256;  Nd = 1024; base = 0; }
  else if (b < 2048) { W = W2; Th = W2Th; Tl = W2Tl; Kd = 1024; Nd = 256;  base = 1024; }
  else               { W = Wv; Th = WvTh; Tl = WvTl; Kd = 256;  Nd = 256;  base = 2048; }
  const int idx = (b - base) * 256 + threadIdx.x;
  const int k = idx % Kd, n = idx / Kd;
  const float w = W[(size_t)k * Nd + n];
  const unsigned short h = f2bf(w);
  Th[(size_t)n * Kd + k] = h;
  Tl[(size_t)n * Kd + k] = f2bf(w - bf2f(h));
}

// GEMM1: H = tanh(x @ W1 + b1).  M=8192 K=256 N=1024.
// 512 thr / 8 waves; tile 128x128; BK=32; wave sub-tile 64x32.
__global__ __launch_bounds__(512, 4) void k_gemm1(
    const float* __restrict__ X, const unsigned short* __restrict__ BTh,
    const unsigned short* __restrict__ BTl, const float* __restrict__ bias,
    unsigned short* __restrict__ Hh, unsigned short* __restrict__ Hl)
{
  const int PIT = 40;  // 32 + 8 pad -> 80B rows, slot stride 5 (odd): conflict-spread
  __shared__ __align__(16) unsigned short As_h[128 * PIT], As_l[128 * PIT];
  __shared__ __align__(16) unsigned short Bs_h[128 * PIT], Bs_l[128 * PIT];
  const int t = threadIdx.x;
  const int n0 = blockIdx.x * 128, m0 = blockIdx.y * 128;
  const int l = t & 63, wid = t >> 6;
  const int wr = wid >> 2, wc = wid & 3;   // wave -> 64x32 sub-tile
  const int kk = (l >> 4) * 8;

  f32x4 acc[4][2] = {};

  for (int k0 = 0; k0 < 256; k0 += 32) {
    // stage A: x tile 128x32 f32 -> hi/lo LDS (2 float4 per thread)
#pragma unroll
    for (int i2 = 0; i2 < 2; ++i2) {
      const int fidx = t + i2 * 512;
      const int row = fidx >> 3, q = fidx & 7;
      const float4 v = *reinterpret_cast<const float4*>(&X[(size_t)(m0 + row) * 256 + k0 + q * 4]);
      unsigned short h0 = f2bf(v.x), h1 = f2bf(v.y), h2 = f2bf(v.z), h3 = f2bf(v.w);
      uint2 hp, lp;
      hp.x = (unsigned)h0 | ((unsigned)h1 << 16);
      hp.y = (unsigned)h2 | ((unsigned)h3 << 16);
      lp.x = (unsigned)f2bf(v.x - bf2f(h0)) | ((unsigned)f2bf(v.y - bf2f(h1)) << 16);
      lp.y = (unsigned)f2bf(v.z - bf2f(h2)) | ((unsigned)f2bf(v.w - bf2f(h3)) << 16);
      *reinterpret_cast<uint2*>(&As_h[row * PIT + q * 4]) = hp;
      *reinterpret_cast<uint2*>(&As_l[row * PIT + q * 4]) = lp;
    }
    // stage B: 128x32 bf16 per half, 1 uint4 per thread per half
    {
      const int row = t >> 2, c4 = t & 3;
      *reinterpret_cast<uint4*>(&Bs_h[row * PIT + c4 * 8]) =
          *reinterpret_cast<const uint4*>(&BTh[(size_t)(n0 + row) * 256 + k0 + c4 * 8]);
      *reinterpret_cast<uint4*>(&Bs_l[row * PIT + c4 * 8]) =
          *reinterpret_cast<const uint4*>(&BTl[(size_t)(n0 + row) * 256 + k0 + c4 * 8]);
    }
    __syncthreads();

    bf16x8 ah[4], al[4], bh[2], bl[2];
#pragma unroll
    for (int i = 0; i < 4; ++i) {
      const int ar = wr * 64 + i * 16 + (l & 15);
      ah[i] = *reinterpret_cast<const bf16x8*>(&As_h[ar * PIT + kk]);
      al[i] = *reinterpret_cast<const bf16x8*>(&As_l[ar * PIT + kk]);
    }
#pragma unroll
    for (int j = 0; j < 2; ++j) {
      const int br = wc * 32 + j * 16 + (l & 15);
      bh[j] = *reinterpret_cast<const bf16x8*>(&Bs_h[br * PIT + kk]);
      bl[j] = *reinterpret_cast<const bf16x8*>(&Bs_l[br * PIT + kk]);
    }
#pragma unroll
    for (int i = 0; i < 4; ++i)
#pragma unroll
      for (int j = 0; j < 2; ++j) {
        acc[i][j] = __builtin_amdgcn_mfma_f32_16x16x32_bf16(ah[i], bh[j], acc[i][j], 0, 0, 0);
        acc[i][j] = __builtin_amdgcn_mfma_f32_16x16x32_bf16(ah[i], bl[j], acc[i][j], 0, 0, 0);
        acc[i][j] = __builtin_amdgcn_mfma_f32_16x16x32_bf16(al[i], bh[j], acc[i][j], 0, 0, 0);
      }
    __syncthreads();
  }

#pragma unroll
  for (int i = 0; i < 4; ++i)
#pragma unroll
    for (int j = 0; j < 2; ++j) {
      const int gn = n0 + wc * 32 + j * 16 + (l & 15);
      const float bv = bias[gn];
#pragma unroll
      for (int r = 0; r < 4; ++r) {
        const int gm = m0 + wr * 64 + i * 16 + (l >> 4) * 4 + r;
        const float tv = tanh_fast(acc[i][j][r] + bv);
        const unsigned short th = f2bf(tv);
        Hh[(size_t)gm * 1024 + gn] = th;
        Hl[(size_t)gm * 1024 + gn] = f2bf(tv - bf2f(th));
      }
    }
}

// GEMM2: out = H @ W2 + b2 + x.  M=8192 K=1024 N=256.
// 512 thr / 8 waves; tile 64x64; BK=64; wave sub-tile 32x16.
__global__ __launch_bounds__(512, 4) void k_gemm2(
    const unsigned short* __restrict__ Ah, const unsigned short* __restrict__ Al,
    const unsigned short* __restrict__ BTh, const unsigned short* __restrict__ BTl,
    const float* __restrict__ bias, const float* __restrict__ X,
    float* __restrict__ OUT)
{
  const int PIT = 72;  // 64 + 8 pad -> 144B rows, slot stride 9 (==1 mod 8): conflict-spread
  __shared__ __align__(16) unsigned short As_h[64 * PIT], As_l[64 * PIT];
  __shared__ __align__(16) unsigned short Bs_h[64 * PIT], Bs_l[64 * PIT];
  const int t = threadIdx.x;
  const int n0 = blockIdx.x * 64, m0 = blockIdx.y * 64;
  const int l = t & 63, wid = t >> 6;
  const int wr = wid >> 2, wc = wid & 3;   // wave -> 32x16 sub-tile
  const int kk = (l >> 4) * 8;
  const int srow = t >> 3, c8 = t & 7;     // staging: 1 uint4 per thread per array

  f32x4 acc[2] = {};

  for (int k0 = 0; k0 < 1024; k0 += 64) {
    *reinterpret_cast<uint4*>(&As_h[srow * PIT + c8 * 8]) =
        *reinterpret_cast<const uint4*>(&Ah[(size_t)(m0 + srow) * 1024 + k0 + c8 * 8]);
    *reinterpret_cast<uint4*>(&As_l[srow * PIT + c8 * 8]) =
        *reinterpret_cast<const uint4*>(&Al[(size_t)(m0 + srow) * 1024 + k0 + c8 * 8]);
    *reinterpret_cast<uint4*>(&Bs_h[srow * PIT + c8 * 8]) =
        *reinterpret_cast<const uint4*>(&BTh[(size_t)(n0 + srow) * 1024 + k0 + c8 * 8]);
    *reinterpret_cast<uint4*>(&Bs_l[srow * PIT + c8 * 8]) =
        *reinterpret_cast<const uint4*>(&BTl[(size_t)(n0 + srow) * 1024 + k0 + c8 * 8]);
    __syncthreads();

#pragma unroll
    for (int ks = 0; ks < 2; ++ks) {
      bf16x8 ah[2], al[2], bh, bl;
      const int ko = ks * 32 + kk;
#pragma unroll
      for (int i = 0; i < 2; ++i) {
        const int ar = wr * 32 + i * 16 + (l & 15);
        ah[i] = *reinterpret_cast<const bf16x8*>(&As_h[ar * PIT + ko]);
        al[i] = *reinterpret_cast<const bf16x8*>(&As_l[ar * PIT + ko]);
      }
      const int br = wc * 16 + (l & 15);
      bh = *reinterpret_cast<const bf16x8*>(&Bs_h[br * PIT + ko]);
      bl = *reinterpret_cast<const bf16x8*>(&Bs_l[br * PIT + ko]);
#pragma unroll
      for (int i = 0; i < 2; ++i) {
        acc[i] = __builtin_amdgcn_mfma_f32_16x16x32_bf16(ah[i], bh, acc[i], 0, 0, 0);
        acc[i] = __builtin_amdgcn_mfma_f32_16x16x32_bf16(ah[i], bl, acc[i], 0, 0, 0);
        acc[i] = __builtin_amdgcn_mfma_f32_16x16x32_bf16(al[i], bh, acc[i], 0, 0, 0);
      }
    }
    __syncthreads();
  }

  const int gn = n0 + wc * 16 + (l & 15);
  const float bv = bias[gn];
#pragma unroll
  for (int i = 0; i < 2; ++i)
#pragma unroll
    for (int r = 0; r < 4; ++r) {
      const int gm = m0 + wr * 32 + i * 16 + (l >> 4) * 4 + r;
      OUT[(size_t)gm * 256 + gn] = acc[i][r] + bv + X[(size_t)gm * 256 + gn];
    }
}

// Fused V + alpha + rescale: Wv fragments in registers (wave owns 32 cols),
// 1 row-tile of 16 samples per block, grid 512.  f32 square-reduce.
__global__ __launch_bounds__(512) void k_valpha(
    const float* __restrict__ X,
    const unsigned short* __restrict__ WvTh, const unsigned short* __restrict__ WvTl,
    float* __restrict__ F)
{
  __shared__ __align__(16) unsigned short Ash[32 * 256];
  __shared__ __align__(16) unsigned short Asl[32 * 256];
  __shared__ float part[2][16][8];
  __shared__ float als[16];
  const int t = threadIdx.x;          // 0..511
  const int l = t & 63, w = t >> 6;   // wave 0..7
  const int c = l & 15, g = l >> 4;
  const int nb = w * 32;

  // prefetch B fragments (block covers all 256 Wv cols)
  bf16x8 bh[2][8], bl[2][8];
#pragma unroll
  for (int nf = 0; nf < 2; ++nf)
#pragma unroll
    for (int ks = 0; ks < 8; ++ks) {
      const int col = nb + nf * 16 + c;
      const int kof = ks * 32 + g * 8;
      bh[nf][ks] = *reinterpret_cast<const bf16x8*>(&WvTh[(size_t)col * 256 + kof]);
      bl[nf][ks] = *reinterpret_cast<const bf16x8*>(&WvTl[(size_t)col * 256 + kof]);
    }

  const int srow = t >> 4;            // 0..31
  const int q = t & 15;
  const int r0 = blockIdx.x * 16;

  // stage A: rows 0..15 = x, 16..31 = f; keep f in regs
  float4 fv[4];
  {
    const float* src = (srow < 16) ? &X[(size_t)(r0 + srow) * 256]
                                   : &F[(size_t)(r0 + srow - 16) * 256];
#pragma unroll
    for (int i = 0; i < 4; ++i) {
      const float4 v = *reinterpret_cast<const float4*>(&src[q * 16 + i * 4]);
      fv[i] = v;
      const unsigned short h0 = f2bf(v.x), h1 = f2bf(v.y), h2 = f2bf(v.z), h3 = f2bf(v.w);
      uint2 hp, lp;
      hp.x = (unsigned)h0 | ((unsigned)h1 << 16);
      hp.y = (unsigned)h2 | ((unsigned)h3 << 16);
      lp.x = (unsigned)f2bf(v.x - bf2f(h0)) | ((unsigned)f2bf(v.y - bf2f(h1)) << 16);
      lp.y = (unsigned)f2bf(v.z - bf2f(h2)) | ((unsigned)f2bf(v.w - bf2f(h3)) << 16);
      const unsigned byte = (unsigned)(srow * 512 + q * 32 + i * 8) ^ ((srow & 7) << 4);
      *reinterpret_cast<uint2*>(((char*)Ash) + byte) = hp;
      *reinterpret_cast<uint2*>(((char*)Asl) + byte) = lp;
    }
  }
  __syncthreads();

  // MFMA: Z = [x;f] @ Wv, square-accumulate f32
  float vs[2][4] = {};
#pragma unroll
  for (int nf = 0; nf < 2; ++nf) {
    f32x4 acc0 = {}, acc1 = {};
#pragma unroll
    for (int ks = 0; ks < 8; ++ks) {
      const int kof = ks * 32 + g * 8;
      const unsigned ab0 = (unsigned)(c * 512 + kof * 2) ^ ((c & 7) << 4);
      const unsigned ab1 = (unsigned)((c + 16) * 512 + kof * 2) ^ ((c & 7) << 4);
      const bf16x8 a0h = *reinterpret_cast<const bf16x8*>(((char*)Ash) + ab0);
      const bf16x8 a0l = *reinterpret_cast<const bf16x8*>(((char*)Asl) + ab0);
      const bf16x8 a1h = *reinterpret_cast<const bf16x8*>(((char*)Ash) + ab1);
      const bf16x8 a1l = *reinterpret_cast<const bf16x8*>(((char*)Asl) + ab1);
      acc0 = __builtin_amdgcn_mfma_f32_16x16x32_bf16(a0h, bh[nf][ks], acc0, 0, 0, 0);
      acc0 = __builtin_amdgcn_mfma_f32_16x16x32_bf16(a0h, bl[nf][ks], acc0, 0, 0, 0);
      acc0 = __builtin_amdgcn_mfma_f32_16x16x32_bf16(a0l, bh[nf][ks], acc0, 0, 0, 0);
      acc1 = __builtin_amdgcn_mfma_f32_16x16x32_bf16(a1h, bh[nf][ks], acc1, 0, 0, 0);
      acc1 = __builtin_amdgcn_mfma_f32_16x16x32_bf16(a1h, bl[nf][ks], acc1, 0, 0, 0);
      acc1 = __builtin_amdgcn_mfma_f32_16x16x32_bf16(a1l, bh[nf][ks], acc1, 0, 0, 0);
    }
#pragma unroll
    for (int r = 0; r < 4; ++r) {
      vs[0][r] = fmaf(acc0[r], acc0[r], vs[0][r]);
      vs[1][r] = fmaf(acc1[r], acc1[r], vs[1][r]);
    }
  }

  // reduce across 16 C-cols (lanes sharing g)
#pragma unroll
  for (int s = 0; s < 2; ++s)
#pragma unroll
    for (int r = 0; r < 4; ++r) {
      float v = vs[s][r];
      v += __shfl_xor(v, 1);
      v += __shfl_xor(v, 2);
      v += __shfl_xor(v, 4);
      v += __shfl_xor(v, 8);
      vs[s][r] = v;
    }
  if (c == 0) {
#pragma unroll
    for (int r = 0; r < 4; ++r) {
      part[0][g * 4 + r][w] = vs[0][r];
      part[1][g * 4 + r][w] = vs[1][r];
    }
  }
  __syncthreads();

  if (t < 16) {
    float Vx = 0.f, Vf = 0.f;
#pragma unroll
    for (int i = 0; i < 8; ++i) { Vx += part[0][t][i]; Vf += part[1][t][i]; }
    const float tt2 = 0.99f * Vx;
    float a;
    if (Vf - tt2 > 0.0f)         a = sqrtf(tt2 / Vf);   // Newton limit
    else if (tt2 - Vf > 1e-4f)   a = 0.5f;              // stuck-bisection case
    else                         a = 1.0f;              // never masked
    als[t] = a;
  }
  __syncthreads();

  if (srow >= 16) {
    const int row = srow - 16;
    const float a = als[row];
    float* dst = &F[(size_t)(r0 + row) * 256];
#pragma unroll
    for (int i = 0; i < 4; ++i) {
      float4 v = fv[i];
      v.x *= a; v.y *= a; v.z *= a; v.w *= a;
      *reinterpret_cast<float4*>(&dst[q * 16 + i * 4]) = v;
    }
  }
}

extern "C" void kernel_launch(void* const* d_in, const int* in_sizes, int n_in,
                              void* d_out, int out_size, void* d_ws, size_t ws_size,
                              hipStream_t stream) {
  const float* x  = (const float*)d_in[0];
  const float* W1 = (const float*)d_in[1];
  const float* b1 = (const float*)d_in[2];
  const float* W2 = (const float*)d_in[3];
  const float* b2 = (const float*)d_in[4];
  const float* Wv = (const float*)d_in[5];
  float* out = (float*)d_out;

  char* ws = (char*)d_ws;
  unsigned short* Hh   = (unsigned short*)(ws);
  unsigned short* Hl   = (unsigned short*)(ws + 16777216);
  unsigned short* W1Th = (unsigned short*)(ws + 33554432);
  unsigned short* W1Tl = (unsigned short*)(ws + 33554432 + 524288);
  unsigned short* W2Th = (unsigned short*)(ws + 33554432 + 2 * 524288);
  unsigned short* W2Tl = (unsigned short*)(ws + 33554432 + 3 * 524288);
  unsigned short* WvTh = (unsigned short*)(ws + 33554432 + 4 * 524288);
  unsigned short* WvTl = (unsigned short*)(ws + 33554432 + 4 * 524288 + 131072);

  k_split_all<<<dim3(2304), dim3(256), 0, stream>>>(W1, W2, Wv, W1Th, W1Tl, W2Th, W2Tl, WvTh, WvTl);

  k_gemm1 <<<dim3(1024 / 128, 8192 / 128), dim3(512), 0, stream>>>(x, W1Th, W1Tl, b1, Hh, Hl);
  k_gemm2 <<<dim3(256 / 64, 8192 / 64), dim3(512), 0, stream>>>(Hh, Hl, W2Th, W2Tl, b2, x, out);
  k_valpha<<<dim3(512), dim3(512), 0, stream>>>(x, WvTh, WvTl, out);
}